// Round 5
// baseline (818.446 us; speedup 1.0000x reference)
//
#include <hip/hip_runtime.h>
#include <math.h>

#define Bb 32
#define Nn 2048
#define Dd 512
#define NS 8
#define ITERS 3
#define EPSf 1e-8f
#define SCALEf 0.04419417382415922f   // 512^-0.5
#define LN_EPSf 1e-5f

#define QHS 520    // qh LDS row stride (halves)
#define PTS 72     // pT LDS row stride (halves)
#define CHUNKS 32  // attention token chunks (64 tokens each)

typedef _Float16 half8 __attribute__((ext_vector_type(8)));
typedef float f32x4 __attribute__((ext_vector_type(4)));

__device__ __forceinline__ float waveReduceSum(float v) {
    #pragma unroll
    for (int m = 32; m >= 1; m >>= 1) v += __shfl_xor(v, m);
    return v;
}

__device__ __forceinline__ float gelu_exact(float x) {
    return 0.5f * x * (1.0f + erff(x * 0.7071067811865476f));
}

__device__ __forceinline__ void async_copy16(const _Float16* g, _Float16* l) {
    __builtin_amdgcn_global_load_lds(
        (const __attribute__((address_space(1))) unsigned int*)g,
        (__attribute__((address_space(3))) unsigned int*)l, 16, 0, 0);
}

// ================= pack kernels =================
__global__ __launch_bounds__(256) void megapack_kernel(
    const float* __restrict__ k_w, const float* __restrict__ v_w,
    const float* __restrict__ w_ih, const float* __restrict__ w_hh,
    const float* __restrict__ m1, const float* __restrict__ m2,
    const float* __restrict__ m3, const float* __restrict__ m4,
    _Float16* __restrict__ Bkv, _Float16* __restrict__ Bih, _Float16* __restrict__ Bhh,
    _Float16* __restrict__ Bm1, _Float16* __restrict__ Bm2,
    _Float16* __restrict__ Bm3, _Float16* __restrict__ Bm4) {
    int bid = blockIdx.x, tid = threadIdx.x;
    const float* src; _Float16* dst; int kbits, base;
    if (bid < 2048) {   // kv plain copy
        int i = bid * 256 + tid;
        Bkv[i] = (_Float16)(i < 262144 ? k_w[i] : v_w[i - 262144]);
        return;
    }
    else if (bid < 5120)  { src = w_ih; dst = Bih; kbits = 9;  base = 2048; }
    else if (bid < 8192)  { src = w_hh; dst = Bhh; kbits = 9;  base = 5120; }
    else if (bid < 10240) { src = m1;   dst = Bm1; kbits = 9;  base = 8192; }
    else if (bid < 14336) { src = m2;   dst = Bm2; kbits = 10; base = 10240; }
    else if (bid < 16384) { src = m3;   dst = Bm3; kbits = 10; base = 14336; }
    else                  { src = m4;   dst = Bm4; kbits = 9;  base = 16384; }
    int e = (bid - base) * 256 + tid;
    int K = 1 << kbits;
    int row = e >> kbits, k = e & (K - 1);
    _Float16 h = (_Float16)src[e];
    _Float16* d = dst + ((size_t)row << (kbits + 1));
    d[k] = h;
    d[K + k] = h;
}

// LN(inputs) -> Apack fp16 [65536][512]
__global__ __launch_bounds__(256) void pack_ln_single_kernel(
    const float* __restrict__ x, const float* __restrict__ g, const float* __restrict__ b,
    _Float16* __restrict__ Ap) {
    int wid = blockIdx.x * 4 + (threadIdx.x >> 6);
    int lane = threadIdx.x & 63;
    const float4* row4 = (const float4*)(x + (size_t)wid * Dd);
    float4 va = row4[lane * 2], vb = row4[lane * 2 + 1];
    float v[8] = {va.x, va.y, va.z, va.w, vb.x, vb.y, vb.z, vb.w};
    float s = 0.f, sq = 0.f;
    #pragma unroll
    for (int t = 0; t < 8; ++t) { s += v[t]; sq += v[t] * v[t]; }
    s = waveReduceSum(s);
    sq = waveReduceSum(sq);
    float m = s * (1.0f / Dd);
    float var = sq * (1.0f / Dd) - m * m;
    float rs = rsqrtf(var + LN_EPSf);
    const float4* g4 = (const float4*)g;
    const float4* b4 = (const float4*)b;
    float4 ga = g4[lane * 2], gb = g4[lane * 2 + 1];
    float4 ba = b4[lane * 2], bb = b4[lane * 2 + 1];
    float gg[8] = {ga.x, ga.y, ga.z, ga.w, gb.x, gb.y, gb.z, gb.w};
    float bbv[8] = {ba.x, ba.y, ba.z, ba.w, bb.x, bb.y, bb.z, bb.w};
    half8 o;
    #pragma unroll
    for (int t = 0; t < 8; ++t) o[t] = (_Float16)((v[t] - m) * rs * gg[t] + bbv[t]);
    *(half8*)(Ap + (size_t)wid * Dd + lane * 8) = o;
}

// slots init (fp32) + pack into A2 slot-half (rows 256..511, hi|lo)
__global__ __launch_bounds__(256) void slots_init_kernel(
    const float* __restrict__ noise, const float* __restrict__ mu,
    const float* __restrict__ ls, float* __restrict__ slots, _Float16* __restrict__ A2) {
    int idx = blockIdx.x * 256 + threadIdx.x;
    if (idx >= Bb * NS * Dd) return;
    int d = idx & (Dd - 1);
    float val = mu[d] + expf(ls[d]) * noise[idx];
    slots[idx] = val;
    int row = idx >> 9;
    _Float16 hi = (_Float16)val;
    A2[(size_t)(256 + row) * 1024 + d] = hi;
    A2[(size_t)(256 + row) * 1024 + 512 + d] = (_Float16)(val - (float)hi);
}

// ================= kv projection: 256x128 tile =================
// flat grid 2048, XCD swizzle: m=(f&7)+8*(f>>6), n=(f>>3)&7 -> the 8 n-copies of
// one A-stripe land on one XCD's L2.
__global__ __launch_bounds__(256) void kv_hgemm_kernel(
    const _Float16* __restrict__ Apack, const _Float16* __restrict__ Bkv,
    const float* __restrict__ k_b, const float* __restrict__ v_b,
    _Float16* __restrict__ khalf, _Float16* __restrict__ vT) {
    __shared__ _Float16 smem[24576];   // As[16384] | Bs[8192] = 48 KB; epilogue reuse 34816 B
    _Float16* As = smem;
    _Float16* Bs = smem + 16384;
    const int f = blockIdx.x;
    const int m0 = ((f & 7) + ((f >> 6) << 3)) * 256;
    const int n0 = ((f >> 3) & 7) * 128;
    const int tid = threadIdx.x;
    const int w = tid >> 6, lane = tid & 63;
    const int r8 = lane >> 3, seg = lane & 7;
    const int lr = lane & 15, quad = lane >> 4;
    const int wm = w >> 1, wn = w & 1;

    f32x4 acc[8][4];
    #pragma unroll
    for (int i = 0; i < 8; ++i)
        #pragma unroll
        for (int j = 0; j < 4; ++j) acc[i][j] = (f32x4){0.f, 0.f, 0.f, 0.f};

    for (int k0 = 0; k0 < 512; k0 += 64) {
        __syncthreads();
        #pragma unroll
        for (int g = 0; g < 12; ++g) {
            int grp = w * 12 + g;                 // 0..47
            if (grp < 32) {                       // A: 256 rows
                int row = grp * 8 + r8;
                async_copy16(Apack + (size_t)(m0 + row) * 512 + k0 + seg * 8, As + grp * 512);
            } else {                              // B: 128 rows
                int brow = (grp - 32) * 8 + r8;
                async_copy16(Bkv + (size_t)(n0 + brow) * 512 + k0 + seg * 8, Bs + (grp - 32) * 512);
            }
        }
        __syncthreads();
        #pragma unroll
        for (int kk = 0; kk < 2; ++kk) {
            half8 a[8], b[4];
            #pragma unroll
            for (int t = 0; t < 8; ++t)
                a[t] = *(const half8*)(As + (wm * 128 + t * 16 + lr) * 64 + kk * 32 + quad * 8);
            #pragma unroll
            for (int u = 0; u < 4; ++u)
                b[u] = *(const half8*)(Bs + (wn * 64 + u * 16 + lr) * 64 + kk * 32 + quad * 8);
            #pragma unroll
            for (int mt = 0; mt < 8; ++mt)
                #pragma unroll
                for (int nt = 0; nt < 4; ++nt)
                    acc[mt][nt] = __builtin_amdgcn_mfma_f32_16x16x32_f16(
                        a[mt], b[nt], acc[mt][nt], 0, 0, 0);
        }
    }
    // epilogue: two passes of 128 m-rows through LDS transpose buffer
    const bool isK = (n0 < 512);
    const int bidx = m0 >> 11;
    #pragma unroll
    for (int p = 0; p < 2; ++p) {
        __syncthreads();
        if (wm == p) {
            #pragma unroll
            for (int mt = 0; mt < 8; ++mt)
                #pragma unroll
                for (int nt = 0; nt < 4; ++nt) {
                    int ml = mt * 16 + quad * 4;          // 0..127 within pass
                    int nl = wn * 64 + nt * 16 + lr;      // 0..127
                    float bv = isK ? k_b[n0 + nl] : v_b[n0 - 512 + nl];
                    #pragma unroll
                    for (int r = 0; r < 4; ++r) {
                        _Float16 h = (_Float16)(acc[mt][nt][r] + bv);
                        if (isK) smem[(ml + r) * 136 + nl] = h;   // [token][d]
                        else     smem[nl * 136 + ml + r] = h;     // [d][token]
                    }
                }
        }
        __syncthreads();
        int r = tid >> 1, half = tid & 1;
        _Float16* dst;
        if (isK) {
            dst = khalf + (size_t)(m0 + p * 128 + r) * 512 + n0 + half * 64;
        } else {
            int j0 = (m0 & 2047) + p * 128;
            dst = vT + ((size_t)bidx * 512 + (n0 - 512) + r) * 2048 + j0 + half * 64;
        }
        #pragma unroll
        for (int c = 0; c < 8; ++c)
            *(half8*)(dst + c * 8) = *(const half8*)(smem + r * 136 + half * 64 + c * 8);
    }
}

// ================= fused attention iteration =================
__global__ __launch_bounds__(256) void attn_kernel(
    const float* __restrict__ slots, const float* __restrict__ ln_g, const float* __restrict__ ln_b,
    const _Float16* __restrict__ khalf, const _Float16* __restrict__ vT,
    float* __restrict__ rawp, float* __restrict__ sumsp) {
    const int b = blockIdx.y, chunk = blockIdx.x;
    __shared__ _Float16 qh[16 * QHS];
    __shared__ _Float16 pT[16 * PTS];
    __shared__ float sums_lds[64];
    const int tid = threadIdx.x, w = tid >> 6, lane = tid & 63;
    const int lr = lane & 15, quad = lane >> 4;

    // LN + scale + fp16 pack of q (8 rows), zero-pad rows 8..15
    #pragma unroll
    for (int rr = 0; rr < 2; ++rr) {
        int row = w * 2 + rr;
        const float* sr = slots + ((size_t)b * NS + row) * Dd;
        float v[8]; float s = 0.f, sq = 0.f;
        #pragma unroll
        for (int t = 0; t < 8; ++t) {
            v[t] = sr[t * 64 + lane];
            s += v[t]; sq += v[t] * v[t];
        }
        s = waveReduceSum(s);
        sq = waveReduceSum(sq);
        float m = s * (1.0f / Dd);
        float var = sq * (1.0f / Dd) - m * m;
        float rs = rsqrtf(var + LN_EPSf);
        #pragma unroll
        for (int t = 0; t < 8; ++t) {
            int d = t * 64 + lane;
            qh[row * QHS + d] = (_Float16)(((v[t] - m) * rs * ln_g[d] + ln_b[d]) * SCALEf);
            qh[(row + 8) * QHS + d] = (_Float16)0.f;
        }
    }
    __syncthreads();

    const int j0 = chunk * 64 + w * 16;
    f32x4 dots = (f32x4){0.f, 0.f, 0.f, 0.f};
    for (int ks = 0; ks < 16; ++ks) {
        half8 bq = *(const half8*)(qh + lr * QHS + ks * 32 + quad * 8);
        half8 ak = *(const half8*)(khalf + ((size_t)b * Nn + j0 + lr) * 512 + ks * 32 + quad * 8);
        dots = __builtin_amdgcn_mfma_f32_16x16x32_f16(ak, bq, dots, 0, 0, 0);
    }
    float ssum = 0.f;
    {
        f32x4 d = dots;
        f32x4 mx = d;
        #pragma unroll
        for (int msk = 1; msk <= 4; msk <<= 1) {
            #pragma unroll
            for (int r = 0; r < 4; ++r) mx[r] = fmaxf(mx[r], __shfl_xor(mx[r], msk));
        }
        f32x4 p;
        #pragma unroll
        for (int r = 0; r < 4; ++r) p[r] = __expf(d[r] - mx[r]);
        f32x4 sm = p;
        #pragma unroll
        for (int msk = 1; msk <= 4; msk <<= 1) {
            #pragma unroll
            for (int r = 0; r < 4; ++r) sm[r] += __shfl_xor(sm[r], msk);
        }
        #pragma unroll
        for (int r = 0; r < 4; ++r) {
            _Float16 ph = (_Float16)(p[r] / sm[r] + EPSf);
            pT[lr * PTS + w * 16 + quad * 4 + r] = ph;
            ssum += (float)ph;
        }
    }
    ssum += __shfl_xor(ssum, 16);
    ssum += __shfl_xor(ssum, 32);
    if (lane < 16) sums_lds[w * 16 + lane] = ssum;
    __syncthreads();

    f32x4 acc[8];
    #pragma unroll
    for (int nf = 0; nf < 8; ++nf) acc[nf] = (f32x4){0.f, 0.f, 0.f, 0.f};
    #pragma unroll
    for (int kc = 0; kc < 2; ++kc) {
        half8 ap = *(const half8*)(pT + lr * PTS + kc * 32 + quad * 8);
        #pragma unroll
        for (int nf = 0; nf < 8; ++nf) {
            int dcol = w * 128 + nf * 16 + lr;
            half8 bv = *(const half8*)(vT + ((size_t)b * 512 + dcol) * 2048 + chunk * 64 + kc * 32 + quad * 8);
            acc[nf] = __builtin_amdgcn_mfma_f32_16x16x32_f16(ap, bv, acc[nf], 0, 0, 0);
        }
    }
    if (quad < 2) {
        #pragma unroll
        for (int nf = 0; nf < 8; ++nf) {
            #pragma unroll
            for (int r = 0; r < 4; ++r) {
                int slot = quad * 4 + r;
                rawp[(((size_t)chunk * Bb + b) * NS + slot) * Dd + w * 128 + nf * 16 + lr] = acc[nf][r];
            }
        }
    }
    if (w == 0 && lane < NS) {
        float tot = sums_lds[lane] + sums_lds[16 + lane] + sums_lds[32 + lane] + sums_lds[48 + lane];
        sumsp[((size_t)chunk * Bb + b) * NS + lane] = tot;
    }
}

// finalize: u = sum_c rawp / sum_c sumsp ; write ubuf, out0, and A2 u-rows (hi|lo)
__global__ __launch_bounds__(256) void finalize_kernel(
    const float* __restrict__ rawp, const float* __restrict__ sumsp,
    float* __restrict__ u, float* __restrict__ out0, _Float16* __restrict__ A2) {
    int idx = blockIdx.x * 256 + threadIdx.x;   // 131072
    int row = idx >> 9, k = idx & 511;
    float rs = 0.f, ss = 0.f;
    #pragma unroll
    for (int c = 0; c < CHUNKS; ++c) {
        rs += rawp[(size_t)c * 131072 + idx];
        ss += sumsp[c * 256 + row];
    }
    float val = rs / ss;
    u[idx] = val;
    out0[idx] = val;
    _Float16 hi = (_Float16)val;
    A2[(size_t)row * 1024 + k] = hi;
    A2[(size_t)row * 1024 + 512 + k] = (_Float16)(val - (float)hi);
}

// ================= barrier-free small GEMM core =================
// 64x64 tile, 4 waves as 2x2, fragments loaded directly from global (L2-resident
// operands; no LDS, no __syncthreads -> fully pipelined K loop).
__device__ __forceinline__ void sgemm_tile(
    const _Float16* __restrict__ A, const _Float16* __restrict__ Bw,
    int m0w, int n0w, int K2, f32x4 acc[2][2]) {
    const int lane = threadIdx.x & 63;
    const int lr = lane & 15, quad = lane >> 4;
    const _Float16* Ap = A + (size_t)(m0w + lr) * K2 + quad * 8;
    const _Float16* Bp = Bw + (size_t)(n0w + lr) * K2 + quad * 8;
    const int steps = K2 >> 5;
    #pragma unroll 4
    for (int ks = 0; ks < steps; ++ks) {
        half8 a0 = *(const half8*)(Ap + ks * 32);
        half8 a1 = *(const half8*)(Ap + (size_t)16 * K2 + ks * 32);
        half8 b0 = *(const half8*)(Bp + ks * 32);
        half8 b1 = *(const half8*)(Bp + (size_t)16 * K2 + ks * 32);
        acc[0][0] = __builtin_amdgcn_mfma_f32_16x16x32_f16(a0, b0, acc[0][0], 0, 0, 0);
        acc[0][1] = __builtin_amdgcn_mfma_f32_16x16x32_f16(a0, b1, acc[0][1], 0, 0, 0);
        acc[1][0] = __builtin_amdgcn_mfma_f32_16x16x32_f16(a1, b0, acc[1][0], 0, 0, 0);
        acc[1][1] = __builtin_amdgcn_mfma_f32_16x16x32_f16(a1, b1, acc[1][1], 0, 0, 0);
    }
}

// generic small gemm: C=act(A@Bw^T+bias); PACK -> write next-layer A (hi|lo, width Kp)
template <int ACT, int PACK>
__global__ __launch_bounds__(256) void sgemm_kernel(
    const _Float16* __restrict__ A, const _Float16* __restrict__ Bw,
    const float* __restrict__ bias, float* __restrict__ C, _Float16* __restrict__ P,
    int K2, int N, int Kp) {
    const int tid = threadIdx.x;
    const int w = tid >> 6, lane = tid & 63;
    const int lr = lane & 15, quad = lane >> 4;
    const int wm = w >> 1, wn = w & 1;
    f32x4 acc[2][2];
    #pragma unroll
    for (int i = 0; i < 2; ++i)
        #pragma unroll
        for (int j = 0; j < 2; ++j) acc[i][j] = (f32x4){0.f, 0.f, 0.f, 0.f};
    sgemm_tile(A, Bw, blockIdx.y * 64 + wm * 32, blockIdx.x * 64 + wn * 32, K2, acc);
    #pragma unroll
    for (int mt = 0; mt < 2; ++mt)
        #pragma unroll
        for (int nt = 0; nt < 2; ++nt) {
            int n = blockIdx.x * 64 + wn * 32 + nt * 16 + lr;
            float bv = bias[n];
            #pragma unroll
            for (int r = 0; r < 4; ++r) {
                int m = blockIdx.y * 64 + wm * 32 + mt * 16 + quad * 4 + r;
                float val = acc[mt][nt][r] + bv;
                if (ACT) val = gelu_exact(val);
                if (PACK) {
                    _Float16 hi = (_Float16)val;
                    P[(size_t)m * 2 * Kp + n] = hi;
                    P[(size_t)m * 2 * Kp + Kp + n] = (_Float16)(val - (float)hi);
                } else {
                    C[(size_t)m * N + n] = val;
                }
            }
        }
}

// GRU gemms, barrier-free: by<4 -> gi = u@w_ih^T (A2 rows 0..255),
// else gh = slots@w_hh^T (A2 rows 256..511)
__global__ __launch_bounds__(256) void gru_gemm_kernel(
    const _Float16* __restrict__ A2, const _Float16* __restrict__ Bih,
    const _Float16* __restrict__ Bhh, const float* __restrict__ b_ih,
    const float* __restrict__ b_hh, float* __restrict__ gi, float* __restrict__ gh) {
    const int by = blockIdx.y;
    const int n0 = blockIdx.x * 64;
    const _Float16* Ap; const _Float16* Bw; const float* bias; float* C; int mb;
    if (by < 4) { Ap = A2;                       Bw = Bih; bias = b_ih; C = gi; mb = by * 64; }
    else        { Ap = A2 + (size_t)256 * 1024;  Bw = Bhh; bias = b_hh; C = gh; mb = (by - 4) * 64; }
    const int tid = threadIdx.x;
    const int w = tid >> 6, lane = tid & 63;
    const int lr = lane & 15, quad = lane >> 4;
    const int wm = w >> 1, wn = w & 1;
    f32x4 acc[2][2];
    #pragma unroll
    for (int i = 0; i < 2; ++i)
        #pragma unroll
        for (int j = 0; j < 2; ++j) acc[i][j] = (f32x4){0.f, 0.f, 0.f, 0.f};
    sgemm_tile(Ap, Bw, mb + wm * 32, n0 + wn * 32, 1024, acc);
    #pragma unroll
    for (int mt = 0; mt < 2; ++mt)
        #pragma unroll
        for (int nt = 0; nt < 2; ++nt) {
            int n = n0 + wn * 32 + nt * 16 + lr;
            float bv = bias[n];
            #pragma unroll
            for (int r = 0; r < 4; ++r) {
                int m = mb + wm * 32 + mt * 16 + quad * 4 + r;
                C[(size_t)m * 1536 + n] = acc[mt][nt][r] + bv;
            }
        }
}

// GRU elementwise, wave-per-row; writes slots + A2 slot-rows; on last iter also LN->P1
__global__ __launch_bounds__(256) void gru_elem_kernel(
    const float* __restrict__ gi, const float* __restrict__ gh,
    const float* __restrict__ u, float* __restrict__ slots, _Float16* __restrict__ A2,
    const float* __restrict__ lnp_g, const float* __restrict__ lnp_b,
    _Float16* __restrict__ P1, int last) {
    int row = blockIdx.x * 4 + (threadIdx.x >> 6);
    int lane = threadIdx.x & 63;
    const float* gir = gi + (size_t)row * 1536;
    const float* ghr = gh + (size_t)row * 1536;
    float val[8];
    #pragma unroll
    for (int t = 0; t < 8; ++t) {
        int d = t * 64 + lane;
        float ir = gir[d], iz = gir[512 + d], in_ = gir[1024 + d];
        float hr = ghr[d], hz = ghr[512 + d], hn = ghr[1024 + d];
        float r = 1.0f / (1.0f + expf(-(ir + hr)));
        float z = 1.0f / (1.0f + expf(-(iz + hz)));
        float n = tanhf(in_ + r * hn);
        float h = slots[(size_t)row * 512 + d];
        float hnew = (1.0f - z) * n + z * h;
        float vv = u[(size_t)row * 512 + d] + hnew;
        val[t] = vv;
        slots[(size_t)row * 512 + d] = vv;
        _Float16 hi = (_Float16)vv;
        A2[(size_t)(256 + row) * 1024 + d] = hi;
        A2[(size_t)(256 + row) * 1024 + 512 + d] = (_Float16)(vv - (float)hi);
    }
    if (last) {
        float s = 0.f, sq = 0.f;
        #pragma unroll
        for (int t = 0; t < 8; ++t) { s += val[t]; sq += val[t] * val[t]; }
        s = waveReduceSum(s);
        sq = waveReduceSum(sq);
        float m = s * (1.0f / Dd);
        float var = sq * (1.0f / Dd) - m * m;
        float rs = rsqrtf(var + LN_EPSf);
        #pragma unroll
        for (int t = 0; t < 8; ++t) {
            int d = t * 64 + lane;
            float a = (val[t] - m) * rs * lnp_g[d] + lnp_b[d];
            _Float16 hi = (_Float16)a;
            P1[(size_t)row * 1024 + d] = hi;
            P1[(size_t)row * 1024 + 512 + d] = (_Float16)(a - (float)hi);
        }
    }
}

// ================= launch =================
extern "C" void kernel_launch(void* const* d_in, const int* in_sizes, int n_in,
                              void* d_out, int out_size, void* d_ws, size_t ws_size,
                              hipStream_t stream) {
    const float* inputs   = (const float*)d_in[0];
    const float* noise    = (const float*)d_in[1];
    const float* mu       = (const float*)d_in[2];
    const float* lsig     = (const float*)d_in[3];
    const float* k_w      = (const float*)d_in[4];
    const float* k_b      = (const float*)d_in[5];
    const float* v_w      = (const float*)d_in[6];
    const float* v_b      = (const float*)d_in[7];
    const float* w_ih     = (const float*)d_in[8];
    const float* w_hh     = (const float*)d_in[9];
    const float* b_ih     = (const float*)d_in[10];
    const float* b_hh     = (const float*)d_in[11];
    const float* ln_in_g  = (const float*)d_in[12];
    const float* ln_in_b  = (const float*)d_in[13];
    const float* ln_s_g   = (const float*)d_in[14];
    const float* ln_s_b   = (const float*)d_in[15];
    const float* ln_p_g   = (const float*)d_in[16];
    const float* ln_p_b   = (const float*)d_in[17];
    const float* mlp1_w   = (const float*)d_in[18];
    const float* mlp1_b   = (const float*)d_in[19];
    const float* mlp2_w   = (const float*)d_in[20];
    const float* mlp2_b   = (const float*)d_in[21];
    const float* mlp3_w   = (const float*)d_in[22];
    const float* mlp3_b   = (const float*)d_in[23];
    const float* mlp4_w   = (const float*)d_in[24];
    const float* mlp4_b   = (const float*)d_in[25];
    float* out0 = (float*)d_out;                 // updates [32,8,512]
    float* out1 = (float*)d_out + Bb * NS * Dd;  // s [32,8,256]

    char* wp = (char*)d_ws;
    auto alloc = [&](size_t bytes) -> void* {
        void* p = (void*)wp;
        wp += (bytes + 255) & ~(size_t)255;
        return p;
    };
    const size_t MR = (size_t)Bb * Nn;  // 65536
    _Float16* Apack = (_Float16*)alloc(MR * 512 * 2);           // 67 MB
    _Float16* khalf = (_Float16*)alloc(MR * 512 * 2);           // 67 MB
    _Float16* vT    = (_Float16*)alloc((size_t)Bb * 512 * Nn * 2); // 67 MB
    _Float16* Bkv   = (_Float16*)alloc((size_t)1024 * 512 * 2);
    _Float16* Bih   = (_Float16*)alloc((size_t)1536 * 1024 * 2);
    _Float16* Bhh   = (_Float16*)alloc((size_t)1536 * 1024 * 2);
    _Float16* Bm1   = (_Float16*)alloc((size_t)1024 * 1024 * 2);
    _Float16* Bm2   = (_Float16*)alloc((size_t)1024 * 2048 * 2);
    _Float16* Bm3   = (_Float16*)alloc((size_t)512 * 2048 * 2);
    _Float16* Bm4   = (_Float16*)alloc((size_t)256 * 1024 * 2);
    float* slots    = (float*)alloc((size_t)Bb * NS * Dd * 4);
    float* rawp     = (float*)alloc((size_t)CHUNKS * Bb * NS * Dd * 4);  // 16 MB
    float* sumsp    = (float*)alloc((size_t)CHUNKS * Bb * NS * 4);
    float* ubuf     = (float*)alloc((size_t)Bb * NS * Dd * 4);
    float* gi       = (float*)alloc((size_t)Bb * NS * 1536 * 4);
    float* gh       = (float*)alloc((size_t)Bb * NS * 1536 * 4);
    _Float16* A2    = (_Float16*)alloc((size_t)512 * 1024 * 2);
    _Float16* P1    = (_Float16*)alloc((size_t)256 * 1024 * 2);
    _Float16* P2    = (_Float16*)alloc((size_t)256 * 2048 * 2);
    _Float16* P3    = (_Float16*)alloc((size_t)256 * 2048 * 2);
    _Float16* P4    = (_Float16*)alloc((size_t)256 * 1024 * 2);

    // ---- prep ----
    megapack_kernel<<<16896, 256, 0, stream>>>(
        k_w, v_w, w_ih, w_hh, mlp1_w, mlp2_w, mlp3_w, mlp4_w,
        Bkv, Bih, Bhh, Bm1, Bm2, Bm3, Bm4);
    pack_ln_single_kernel<<<MR / 4, 256, 0, stream>>>(inputs, ln_in_g, ln_in_b, Apack);
    slots_init_kernel<<<(Bb * NS * Dd) / 256, 256, 0, stream>>>(noise, mu, lsig, slots, A2);

    kv_hgemm_kernel<<<2048, 256, 0, stream>>>(Apack, Bkv, k_b, v_b, khalf, vT);

    for (int it = 0; it < ITERS; ++it) {
        attn_kernel<<<dim3(CHUNKS, Bb), 256, 0, stream>>>(slots, ln_s_g, ln_s_b, khalf, vT, rawp, sumsp);
        finalize_kernel<<<512, 256, 0, stream>>>(rawp, sumsp, ubuf, out0, A2);
        gru_gemm_kernel<<<dim3(24, 8), 256, 0, stream>>>(A2, Bih, Bhh, b_ih, b_hh, gi, gh);
        gru_elem_kernel<<<64, 256, 0, stream>>>(gi, gh, ubuf, slots, A2,
                                                ln_p_g, ln_p_b, P1, it == ITERS - 1 ? 1 : 0);
    }

    // ---- output MLP ----
    sgemm_kernel<1, 1><<<dim3(16, 4), 256, 0, stream>>>(P1, Bm1, mlp1_b, nullptr, P2, 1024, 1024, 1024);
    sgemm_kernel<1, 1><<<dim3(16, 4), 256, 0, stream>>>(P2, Bm2, mlp2_b, nullptr, P3, 2048, 1024, 1024);
    sgemm_kernel<1, 1><<<dim3(8, 4), 256, 0, stream>>>(P3, Bm3, mlp3_b, nullptr, P4, 2048, 512, 512);
    sgemm_kernel<0, 0><<<dim3(4, 4), 256, 0, stream>>>(P4, Bm4, mlp4_b, out1, nullptr, 1024, 256, 256);
}

// Round 6
// 652.580 us; speedup vs baseline: 1.2542x; 1.2542x over previous
//
#include <hip/hip_runtime.h>
#include <math.h>

#define Bb 32
#define Nn 2048
#define Dd 512
#define NS 8
#define ITERS 3
#define EPSf 1e-8f
#define SCALEf 0.04419417382415922f   // 512^-0.5
#define LN_EPSf 1e-5f

#define QHS 520    // qh LDS row stride (halves)
#define PTS 136    // pT LDS row stride (halves)
#define CHUNKS 16  // attention token chunks (128 tokens each)

typedef _Float16 half8 __attribute__((ext_vector_type(8)));
typedef float f32x4 __attribute__((ext_vector_type(4)));

__device__ __forceinline__ float waveReduceSum(float v) {
    #pragma unroll
    for (int m = 32; m >= 1; m >>= 1) v += __shfl_xor(v, m);
    return v;
}

__device__ __forceinline__ float gelu_exact(float x) {
    return 0.5f * x * (1.0f + erff(x * 0.7071067811865476f));
}

__device__ __forceinline__ void async_copy16(const _Float16* g, _Float16* l) {
    __builtin_amdgcn_global_load_lds(
        (const __attribute__((address_space(1))) unsigned int*)g,
        (__attribute__((address_space(3))) unsigned int*)l, 16, 0, 0);
}

// ================= pack kernels =================
__global__ __launch_bounds__(256) void megapack_kernel(
    const float* __restrict__ k_w, const float* __restrict__ v_w,
    const float* __restrict__ w_ih, const float* __restrict__ w_hh,
    const float* __restrict__ m1, const float* __restrict__ m2,
    const float* __restrict__ m3, const float* __restrict__ m4,
    _Float16* __restrict__ Bkv, _Float16* __restrict__ Bih, _Float16* __restrict__ Bhh,
    _Float16* __restrict__ Bm1, _Float16* __restrict__ Bm2,
    _Float16* __restrict__ Bm3, _Float16* __restrict__ Bm4) {
    int bid = blockIdx.x, tid = threadIdx.x;
    const float* src; _Float16* dst; int kbits, base;
    if (bid < 2048) {   // kv plain copy
        int i = bid * 256 + tid;
        Bkv[i] = (_Float16)(i < 262144 ? k_w[i] : v_w[i - 262144]);
        return;
    }
    else if (bid < 5120)  { src = w_ih; dst = Bih; kbits = 9;  base = 2048; }
    else if (bid < 8192)  { src = w_hh; dst = Bhh; kbits = 9;  base = 5120; }
    else if (bid < 10240) { src = m1;   dst = Bm1; kbits = 9;  base = 8192; }
    else if (bid < 14336) { src = m2;   dst = Bm2; kbits = 10; base = 10240; }
    else if (bid < 16384) { src = m3;   dst = Bm3; kbits = 10; base = 14336; }
    else                  { src = m4;   dst = Bm4; kbits = 9;  base = 16384; }
    int e = (bid - base) * 256 + tid;
    int K = 1 << kbits;
    int row = e >> kbits, k = e & (K - 1);
    _Float16 h = (_Float16)src[e];
    _Float16* d = dst + ((size_t)row << (kbits + 1));
    d[k] = h;
    d[K + k] = h;
}

// LN(inputs) -> Apack fp16 [65536][512]
__global__ __launch_bounds__(256) void pack_ln_single_kernel(
    const float* __restrict__ x, const float* __restrict__ g, const float* __restrict__ b,
    _Float16* __restrict__ Ap) {
    int wid = blockIdx.x * 4 + (threadIdx.x >> 6);
    int lane = threadIdx.x & 63;
    const float4* row4 = (const float4*)(x + (size_t)wid * Dd);
    float4 va = row4[lane * 2], vb = row4[lane * 2 + 1];
    float v[8] = {va.x, va.y, va.z, va.w, vb.x, vb.y, vb.z, vb.w};
    float s = 0.f, sq = 0.f;
    #pragma unroll
    for (int t = 0; t < 8; ++t) { s += v[t]; sq += v[t] * v[t]; }
    s = waveReduceSum(s);
    sq = waveReduceSum(sq);
    float m = s * (1.0f / Dd);
    float var = sq * (1.0f / Dd) - m * m;
    float rs = rsqrtf(var + LN_EPSf);
    const float4* g4 = (const float4*)g;
    const float4* b4 = (const float4*)b;
    float4 ga = g4[lane * 2], gb = g4[lane * 2 + 1];
    float4 ba = b4[lane * 2], bb = b4[lane * 2 + 1];
    float gg[8] = {ga.x, ga.y, ga.z, ga.w, gb.x, gb.y, gb.z, gb.w};
    float bbv[8] = {ba.x, ba.y, ba.z, ba.w, bb.x, bb.y, bb.z, bb.w};
    half8 o;
    #pragma unroll
    for (int t = 0; t < 8; ++t) o[t] = (_Float16)((v[t] - m) * rs * gg[t] + bbv[t]);
    *(half8*)(Ap + (size_t)wid * Dd + lane * 8) = o;
}

// slots init, wave-per-row: slots fp32, A2 slot-rows (hi|lo), qh = LN(slots)*scale fp16
__global__ __launch_bounds__(256) void slots_init_kernel(
    const float* __restrict__ noise, const float* __restrict__ mu,
    const float* __restrict__ ls, float* __restrict__ slots, _Float16* __restrict__ A2,
    const float* __restrict__ lns_g, const float* __restrict__ lns_b,
    _Float16* __restrict__ qh) {
    int row = blockIdx.x * 4 + (threadIdx.x >> 6);
    int lane = threadIdx.x & 63;
    float val[8];
    float s = 0.f, sq = 0.f;
    #pragma unroll
    for (int t = 0; t < 8; ++t) {
        int d = t * 64 + lane;
        float v = mu[d] + expf(ls[d]) * noise[(size_t)row * 512 + d];
        val[t] = v;
        s += v; sq += v * v;
        slots[(size_t)row * 512 + d] = v;
        _Float16 hi = (_Float16)v;
        A2[(size_t)(256 + row) * 1024 + d] = hi;
        A2[(size_t)(256 + row) * 1024 + 512 + d] = (_Float16)(v - (float)hi);
    }
    s = waveReduceSum(s);
    sq = waveReduceSum(sq);
    float m = s * (1.0f / Dd);
    float var = sq * (1.0f / Dd) - m * m;
    float rs = rsqrtf(var + LN_EPSf);
    #pragma unroll
    for (int t = 0; t < 8; ++t) {
        int d = t * 64 + lane;
        qh[(size_t)row * 512 + d] = (_Float16)(((val[t] - m) * rs * lns_g[d] + lns_b[d]) * SCALEf);
    }
}

// ================= kv projection: 128x128 tile, XCD swizzle (R4 best) =================
__global__ __launch_bounds__(256) void kv_hgemm_kernel(
    const _Float16* __restrict__ Apack, const _Float16* __restrict__ Bkv,
    const float* __restrict__ k_b, const float* __restrict__ v_b,
    _Float16* __restrict__ khalf, _Float16* __restrict__ vT) {
    __shared__ _Float16 smem[17408];   // As[8192] | Bs[8192], reused as Ct[128][136]
    _Float16* As = smem;
    _Float16* Bs = smem + 8192;
    const int f = blockIdx.x;
    const int m0 = ((f & 7) + ((f >> 6) << 3)) * 128;
    const int n0 = ((f >> 3) & 7) * 128;
    const int tid = threadIdx.x;
    const int w = tid >> 6, lane = tid & 63;
    const int r8 = lane >> 3, seg = lane & 7;
    const int lr = lane & 15, quad = lane >> 4;
    const int wm = w >> 1, wn = w & 1;
    f32x4 acc[4][4];
    #pragma unroll
    for (int i = 0; i < 4; ++i)
        #pragma unroll
        for (int j = 0; j < 4; ++j) acc[i][j] = (f32x4){0.f, 0.f, 0.f, 0.f};
    for (int k0 = 0; k0 < 512; k0 += 64) {
        __syncthreads();
        #pragma unroll
        for (int g = 0; g < 4; ++g) {
            int grp = w * 4 + g;
            int row = grp * 8 + r8;
            async_copy16(Apack + (size_t)(m0 + row) * 512 + k0 + seg * 8, As + grp * 512);
            async_copy16(Bkv + (size_t)(n0 + row) * 512 + k0 + seg * 8, Bs + grp * 512);
        }
        __syncthreads();
        #pragma unroll
        for (int kk = 0; kk < 2; ++kk) {
            half8 a[4], b[4];
            #pragma unroll
            for (int t = 0; t < 4; ++t) {
                a[t] = *(const half8*)(As + (wm * 64 + t * 16 + lr) * 64 + kk * 32 + quad * 8);
                b[t] = *(const half8*)(Bs + (wn * 64 + t * 16 + lr) * 64 + kk * 32 + quad * 8);
            }
            #pragma unroll
            for (int mt = 0; mt < 4; ++mt)
                #pragma unroll
                for (int nt = 0; nt < 4; ++nt)
                    acc[mt][nt] = __builtin_amdgcn_mfma_f32_16x16x32_f16(
                        a[mt], b[nt], acc[mt][nt], 0, 0, 0);
        }
    }
    __syncthreads();
    const bool isK = (n0 < 512);
    #pragma unroll
    for (int mt = 0; mt < 4; ++mt)
        #pragma unroll
        for (int nt = 0; nt < 4; ++nt) {
            int ml = wm * 64 + mt * 16 + quad * 4;
            int nl = wn * 64 + nt * 16 + lr;
            float bv = isK ? k_b[n0 + nl] : v_b[n0 - 512 + nl];
            #pragma unroll
            for (int r = 0; r < 4; ++r) {
                _Float16 h = (_Float16)(acc[mt][nt][r] + bv);
                if (isK) smem[(ml + r) * 136 + nl] = h;    // [token][d]
                else     smem[nl * 136 + ml + r] = h;      // [d][token]
            }
        }
    __syncthreads();
    int r = tid >> 1, half = tid & 1;
    _Float16* dst;
    if (isK) {
        dst = khalf + (size_t)(m0 + r) * 512 + n0 + half * 64;
    } else {
        int b = m0 >> 11, j0 = m0 & 2047, d0 = n0 - 512;
        dst = vT + ((size_t)b * 512 + d0 + r) * 2048 + j0 + half * 64;
    }
    #pragma unroll
    for (int c = 0; c < 8; ++c)
        *(half8*)(dst + c * 8) = *(const half8*)(smem + r * 136 + half * 64 + c * 8);
}

// ================= fused attention iteration (R3 shape, qh from global) =================
__global__ __launch_bounds__(256) void attn_kernel(
    const _Float16* __restrict__ qh_g,
    const _Float16* __restrict__ khalf, const _Float16* __restrict__ vT,
    float* __restrict__ rawp, float* __restrict__ sumsp) {
    const int b = blockIdx.y, chunk = blockIdx.x;
    __shared__ _Float16 qh[16 * QHS];
    __shared__ _Float16 pT[16 * PTS];
    __shared__ float sums_lds[64];
    const int tid = threadIdx.x, w = tid >> 6, lane = tid & 63;
    const int lr = lane & 15, quad = lane >> 4;

    // copy qh rows 0..7 (8 KB) from global; zero rows 8..15
    {
        int r = tid >> 5;               // 0..7
        int c = (tid & 31) * 16;        // 0..496
        *(half8*)(qh + r * QHS + c) = *(const half8*)(qh_g + ((size_t)b * NS + r) * 512 + c);
        *(half8*)(qh + r * QHS + c + 8) = *(const half8*)(qh_g + ((size_t)b * NS + r) * 512 + c + 8);
        half8 z = {};
        *(half8*)(qh + (8 + r) * QHS + c) = z;
        *(half8*)(qh + (8 + r) * QHS + c + 8) = z;
    }
    __syncthreads();

    // QK: wave handles 32 tokens; A=k rows (m=token), B=qh (n=slot)
    const int j0 = chunk * 128 + w * 32;
    f32x4 dots[2];
    dots[0] = (f32x4){0.f, 0.f, 0.f, 0.f};
    dots[1] = (f32x4){0.f, 0.f, 0.f, 0.f};
    for (int ks = 0; ks < 16; ++ks) {
        half8 bq = *(const half8*)(qh + lr * QHS + ks * 32 + quad * 8);
        #pragma unroll
        for (int mf = 0; mf < 2; ++mf) {
            half8 ak = *(const half8*)(khalf + ((size_t)b * Nn + j0 + mf * 16 + lr) * 512 + ks * 32 + quad * 8);
            dots[mf] = __builtin_amdgcn_mfma_f32_16x16x32_f16(ak, bq, dots[mf], 0, 0, 0);
        }
    }
    // softmax over slots
    float ssum = 0.f;
    #pragma unroll
    for (int mf = 0; mf < 2; ++mf) {
        f32x4 d = dots[mf];
        f32x4 mx = d;
        #pragma unroll
        for (int msk = 1; msk <= 4; msk <<= 1) {
            #pragma unroll
            for (int r = 0; r < 4; ++r) mx[r] = fmaxf(mx[r], __shfl_xor(mx[r], msk));
        }
        f32x4 p;
        #pragma unroll
        for (int r = 0; r < 4; ++r) p[r] = __expf(d[r] - mx[r]);
        f32x4 sm = p;
        #pragma unroll
        for (int msk = 1; msk <= 4; msk <<= 1) {
            #pragma unroll
            for (int r = 0; r < 4; ++r) sm[r] += __shfl_xor(sm[r], msk);
        }
        #pragma unroll
        for (int r = 0; r < 4; ++r) {
            _Float16 ph = (_Float16)(p[r] / sm[r] + EPSf);
            pT[lr * PTS + w * 32 + mf * 16 + quad * 4 + r] = ph;
            ssum += (float)ph;
        }
    }
    ssum += __shfl_xor(ssum, 16);
    ssum += __shfl_xor(ssum, 32);
    if (lane < 16) sums_lds[w * 16 + lane] = ssum;
    __syncthreads();

    // PV: A = P^T (m=slot, k=token), B = vT (n=d); wave covers d-range w*128
    f32x4 acc[8];
    #pragma unroll
    for (int nf = 0; nf < 8; ++nf) acc[nf] = (f32x4){0.f, 0.f, 0.f, 0.f};
    #pragma unroll
    for (int kc = 0; kc < 4; ++kc) {
        half8 ap = *(const half8*)(pT + lr * PTS + kc * 32 + quad * 8);
        #pragma unroll
        for (int nf = 0; nf < 8; ++nf) {
            int dcol = w * 128 + nf * 16 + lr;
            half8 bv = *(const half8*)(vT + ((size_t)b * 512 + dcol) * 2048 + chunk * 128 + kc * 32 + quad * 8);
            acc[nf] = __builtin_amdgcn_mfma_f32_16x16x32_f16(ap, bv, acc[nf], 0, 0, 0);
        }
    }
    if (quad < 2) {
        #pragma unroll
        for (int nf = 0; nf < 8; ++nf) {
            #pragma unroll
            for (int r = 0; r < 4; ++r) {
                int slot = quad * 4 + r;
                rawp[(((size_t)chunk * Bb + b) * NS + slot) * Dd + w * 128 + nf * 16 + lr] = acc[nf][r];
            }
        }
    }
    if (w == 0 && lane < NS) {
        float tot = sums_lds[lane] + sums_lds[16 + lane] + sums_lds[32 + lane] + sums_lds[48 + lane];
        sumsp[((size_t)chunk * Bb + b) * NS + lane] = tot;
    }
}

// finalize: u = sum_c rawp / sum_c sumsp ; write ubuf, out0, and A2 u-rows (hi|lo)
__global__ __launch_bounds__(256) void finalize_kernel(
    const float* __restrict__ rawp, const float* __restrict__ sumsp,
    float* __restrict__ u, float* __restrict__ out0, _Float16* __restrict__ A2) {
    int idx = blockIdx.x * 256 + threadIdx.x;   // 131072
    int row = idx >> 9, k = idx & 511;
    float rs = 0.f, ss = 0.f;
    #pragma unroll
    for (int c = 0; c < CHUNKS; ++c) {
        rs += rawp[(size_t)c * 131072 + idx];
        ss += sumsp[c * 256 + row];
    }
    float val = rs / ss;
    u[idx] = val;
    out0[idx] = val;
    _Float16 hi = (_Float16)val;
    A2[(size_t)row * 1024 + k] = hi;
    A2[(size_t)row * 1024 + 512 + k] = (_Float16)(val - (float)hi);
}

// ================= 64-tile MFMA core (small gemms, LDS-staged — R3 best) =================
__device__ __forceinline__ void hgemm64_core(
    const _Float16* __restrict__ A, const _Float16* __restrict__ Bw,
    int K2, f32x4 acc[2][2], _Float16* As, _Float16* Bs) {
    const int tid = threadIdx.x;
    const int w = tid >> 6, lane = tid & 63;
    const int r8 = lane >> 3, seg = lane & 7;
    const int lr = lane & 15, quad = lane >> 4;
    const int wm = w >> 1, wn = w & 1;
    for (int k0 = 0; k0 < K2; k0 += 64) {
        __syncthreads();
        #pragma unroll
        for (int p = 0; p < 2; ++p) {
            int grp = p * 4 + w;
            int row = grp * 8 + r8;
            async_copy16(A + (size_t)row * K2 + k0 + seg * 8, As + grp * 512);
            async_copy16(Bw + (size_t)row * K2 + k0 + seg * 8, Bs + grp * 512);
        }
        __syncthreads();
        #pragma unroll
        for (int kk = 0; kk < 2; ++kk) {
            half8 a[2], b[2];
            #pragma unroll
            for (int t = 0; t < 2; ++t) {
                a[t] = *(const half8*)(As + (wm * 32 + t * 16 + lr) * 64 + kk * 32 + quad * 8);
                b[t] = *(const half8*)(Bs + (wn * 32 + t * 16 + lr) * 64 + kk * 32 + quad * 8);
            }
            #pragma unroll
            for (int mt = 0; mt < 2; ++mt)
                #pragma unroll
                for (int nt = 0; nt < 2; ++nt)
                    acc[mt][nt] = __builtin_amdgcn_mfma_f32_16x16x32_f16(
                        a[mt], b[nt], acc[mt][nt], 0, 0, 0);
        }
    }
}

// generic 64-tile gemm: C=act(A@Bw^T+bias); PACK -> write next-layer A (hi|lo, width Kp)
template <int ACT, int PACK>
__global__ __launch_bounds__(256) void hgemm64_kernel(
    const _Float16* __restrict__ A, const _Float16* __restrict__ Bw,
    const float* __restrict__ bias, float* __restrict__ C, _Float16* __restrict__ P,
    int K2, int N, int Kp) {
    __shared__ _Float16 As[4096], Bs[4096];
    const int m0 = blockIdx.y * 64, n0 = blockIdx.x * 64;
    f32x4 acc[2][2];
    #pragma unroll
    for (int i = 0; i < 2; ++i)
        #pragma unroll
        for (int j = 0; j < 2; ++j) acc[i][j] = (f32x4){0.f, 0.f, 0.f, 0.f};
    hgemm64_core(A + (size_t)m0 * K2, Bw + (size_t)n0 * K2, K2, acc, As, Bs);
    const int tid = threadIdx.x;
    const int w = tid >> 6, lane = tid & 63;
    const int lr = lane & 15, quad = lane >> 4;
    const int wm = w >> 1, wn = w & 1;
    #pragma unroll
    for (int mt = 0; mt < 2; ++mt)
        #pragma unroll
        for (int nt = 0; nt < 2; ++nt) {
            int n = n0 + wn * 32 + nt * 16 + lr;
            float bv = bias[n];
            #pragma unroll
            for (int r = 0; r < 4; ++r) {
                int m = m0 + wm * 32 + mt * 16 + quad * 4 + r;
                float val = acc[mt][nt][r] + bv;
                if (ACT) val = gelu_exact(val);
                if (PACK) {
                    _Float16 hi = (_Float16)val;
                    P[(size_t)m * 2 * Kp + n] = hi;
                    P[(size_t)m * 2 * Kp + Kp + n] = (_Float16)(val - (float)hi);
                } else {
                    C[(size_t)m * N + n] = val;
                }
            }
        }
}

// GRU gemms: by<4 -> gi = u@w_ih^T (A2 rows 0..255), else gh = slots@w_hh^T (rows 256..511)
__global__ __launch_bounds__(256) void gru_gemm_kernel(
    const _Float16* __restrict__ A2, const _Float16* __restrict__ Bih,
    const _Float16* __restrict__ Bhh, const float* __restrict__ b_ih,
    const float* __restrict__ b_hh, float* __restrict__ gi, float* __restrict__ gh) {
    __shared__ _Float16 As[4096], Bs[4096];
    const int by = blockIdx.y;
    const int n0 = blockIdx.x * 64;
    const _Float16* Ap; const _Float16* Bw; const float* bias; float* C;
    if (by < 4) { Ap = A2 + (size_t)by * 64 * 1024;        Bw = Bih; bias = b_ih; C = gi + (size_t)by * 64 * 1536; }
    else        { Ap = A2 + (size_t)(256 + (by - 4) * 64) * 1024; Bw = Bhh; bias = b_hh; C = gh + (size_t)(by - 4) * 64 * 1536; }
    f32x4 acc[2][2];
    #pragma unroll
    for (int i = 0; i < 2; ++i)
        #pragma unroll
        for (int j = 0; j < 2; ++j) acc[i][j] = (f32x4){0.f, 0.f, 0.f, 0.f};
    hgemm64_core(Ap, Bw + (size_t)n0 * 1024, 1024, acc, As, Bs);
    const int tid = threadIdx.x;
    const int w = tid >> 6, lane = tid & 63;
    const int lr = lane & 15, quad = lane >> 4;
    const int wm = w >> 1, wn = w & 1;
    #pragma unroll
    for (int mt = 0; mt < 2; ++mt)
        #pragma unroll
        for (int nt = 0; nt < 2; ++nt) {
            int n = n0 + wn * 32 + nt * 16 + lr;
            float bv = bias[n];
            #pragma unroll
            for (int r = 0; r < 4; ++r) {
                int m = wm * 32 + mt * 16 + quad * 4 + r;
                C[(size_t)m * 1536 + n] = acc[mt][nt][r] + bv;
            }
        }
}

// GRU elementwise, wave-per-row; slots + A2 slot-rows; qh for next iter, or P1 on last
__global__ __launch_bounds__(256) void gru_elem_kernel(
    const float* __restrict__ gi, const float* __restrict__ gh,
    const float* __restrict__ u, float* __restrict__ slots, _Float16* __restrict__ A2,
    const float* __restrict__ lns_g, const float* __restrict__ lns_b,
    _Float16* __restrict__ qh,
    const float* __restrict__ lnp_g, const float* __restrict__ lnp_b,
    _Float16* __restrict__ P1, int last) {
    int row = blockIdx.x * 4 + (threadIdx.x >> 6);
    int lane = threadIdx.x & 63;
    const float* gir = gi + (size_t)row * 1536;
    const float* ghr = gh + (size_t)row * 1536;
    float val[8];
    #pragma unroll
    for (int t = 0; t < 8; ++t) {
        int d = t * 64 + lane;
        float ir = gir[d], iz = gir[512 + d], in_ = gir[1024 + d];
        float hr = ghr[d], hz = ghr[512 + d], hn = ghr[1024 + d];
        float r = 1.0f / (1.0f + expf(-(ir + hr)));
        float z = 1.0f / (1.0f + expf(-(iz + hz)));
        float n = tanhf(in_ + r * hn);
        float h = slots[(size_t)row * 512 + d];
        float hnew = (1.0f - z) * n + z * h;
        float vv = u[(size_t)row * 512 + d] + hnew;
        val[t] = vv;
        slots[(size_t)row * 512 + d] = vv;
        _Float16 hi = (_Float16)vv;
        A2[(size_t)(256 + row) * 1024 + d] = hi;
        A2[(size_t)(256 + row) * 1024 + 512 + d] = (_Float16)(vv - (float)hi);
    }
    float s = 0.f, sq = 0.f;
    #pragma unroll
    for (int t = 0; t < 8; ++t) { s += val[t]; sq += val[t] * val[t]; }
    s = waveReduceSum(s);
    sq = waveReduceSum(sq);
    float m = s * (1.0f / Dd);
    float var = sq * (1.0f / Dd) - m * m;
    float rs = rsqrtf(var + LN_EPSf);
    if (!last) {
        #pragma unroll
        for (int t = 0; t < 8; ++t) {
            int d = t * 64 + lane;
            qh[(size_t)row * 512 + d] =
                (_Float16)(((val[t] - m) * rs * lns_g[d] + lns_b[d]) * SCALEf);
        }
    } else {
        #pragma unroll
        for (int t = 0; t < 8; ++t) {
            int d = t * 64 + lane;
            float a = (val[t] - m) * rs * lnp_g[d] + lnp_b[d];
            _Float16 hi = (_Float16)a;
            P1[(size_t)row * 1024 + d] = hi;
            P1[(size_t)row * 1024 + 512 + d] = (_Float16)(a - (float)hi);
        }
    }
}

// ================= launch =================
extern "C" void kernel_launch(void* const* d_in, const int* in_sizes, int n_in,
                              void* d_out, int out_size, void* d_ws, size_t ws_size,
                              hipStream_t stream) {
    const float* inputs   = (const float*)d_in[0];
    const float* noise    = (const float*)d_in[1];
    const float* mu       = (const float*)d_in[2];
    const float* lsig     = (const float*)d_in[3];
    const float* k_w      = (const float*)d_in[4];
    const float* k_b      = (const float*)d_in[5];
    const float* v_w      = (const float*)d_in[6];
    const float* v_b      = (const float*)d_in[7];
    const float* w_ih     = (const float*)d_in[8];
    const float* w_hh     = (const float*)d_in[9];
    const float* b_ih     = (const float*)d_in[10];
    const float* b_hh     = (const float*)d_in[11];
    const float* ln_in_g  = (const float*)d_in[12];
    const float* ln_in_b  = (const float*)d_in[13];
    const float* ln_s_g   = (const float*)d_in[14];
    const float* ln_s_b   = (const float*)d_in[15];
    const float* ln_p_g   = (const float*)d_in[16];
    const float* ln_p_b   = (const float*)d_in[17];
    const float* mlp1_w   = (const float*)d_in[18];
    const float* mlp1_b   = (const float*)d_in[19];
    const float* mlp2_w   = (const float*)d_in[20];
    const float* mlp2_b   = (const float*)d_in[21];
    const float* mlp3_w   = (const float*)d_in[22];
    const float* mlp3_b   = (const float*)d_in[23];
    const float* mlp4_w   = (const float*)d_in[24];
    const float* mlp4_b   = (const float*)d_in[25];
    float* out0 = (float*)d_out;                 // updates [32,8,512]
    float* out1 = (float*)d_out + Bb * NS * Dd;  // s [32,8,256]

    char* wp = (char*)d_ws;
    auto alloc = [&](size_t bytes) -> void* {
        void* p = (void*)wp;
        wp += (bytes + 255) & ~(size_t)255;
        return p;
    };
    const size_t MR = (size_t)Bb * Nn;  // 65536
    _Float16* Apack = (_Float16*)alloc(MR * 512 * 2);           // 67 MB
    _Float16* khalf = (_Float16*)alloc(MR * 512 * 2);           // 67 MB
    _Float16* vT    = (_Float16*)alloc((size_t)Bb * 512 * Nn * 2); // 67 MB
    _Float16* Bkv   = (_Float16*)alloc((size_t)1024 * 512 * 2);
    _Float16* Bih   = (_Float16*)alloc((size_t)1536 * 1024 * 2);
    _Float16* Bhh   = (_Float16*)alloc((size_t)1536 * 1024 * 2);
    _Float16* Bm1   = (_Float16*)alloc((size_t)1024 * 1024 * 2);
    _Float16* Bm2   = (_Float16*)alloc((size_t)1024 * 2048 * 2);
    _Float16* Bm3   = (_Float16*)alloc((size_t)512 * 2048 * 2);
    _Float16* Bm4   = (_Float16*)alloc((size_t)256 * 1024 * 2);
    float* slots    = (float*)alloc((size_t)Bb * NS * Dd * 4);
    _Float16* qh    = (_Float16*)alloc((size_t)Bb * NS * Dd * 2);
    float* rawp     = (float*)alloc((size_t)CHUNKS * Bb * NS * Dd * 4);  // 8 MB
    float* sumsp    = (float*)alloc((size_t)CHUNKS * Bb * NS * 4);
    float* ubuf     = (float*)alloc((size_t)Bb * NS * Dd * 4);
    float* gi       = (float*)alloc((size_t)Bb * NS * 1536 * 4);
    float* gh       = (float*)alloc((size_t)Bb * NS * 1536 * 4);
    _Float16* A2    = (_Float16*)alloc((size_t)512 * 1024 * 2);
    _Float16* P1    = (_Float16*)alloc((size_t)256 * 1024 * 2);
    _Float16* P2    = (_Float16*)alloc((size_t)256 * 2048 * 2);
    _Float16* P3    = (_Float16*)alloc((size_t)256 * 2048 * 2);
    _Float16* P4    = (_Float16*)alloc((size_t)256 * 1024 * 2);

    // ---- prep ----
    megapack_kernel<<<16896, 256, 0, stream>>>(
        k_w, v_w, w_ih, w_hh, mlp1_w, mlp2_w, mlp3_w, mlp4_w,
        Bkv, Bih, Bhh, Bm1, Bm2, Bm3, Bm4);
    pack_ln_single_kernel<<<MR / 4, 256, 0, stream>>>(inputs, ln_in_g, ln_in_b, Apack);
    slots_init_kernel<<<64, 256, 0, stream>>>(noise, mu, lsig, slots, A2, ln_s_g, ln_s_b, qh);

    kv_hgemm_kernel<<<4096, 256, 0, stream>>>(Apack, Bkv, k_b, v_b, khalf, vT);

    for (int it = 0; it < ITERS; ++it) {
        attn_kernel<<<dim3(CHUNKS, Bb), 256, 0, stream>>>(qh, khalf, vT, rawp, sumsp);
        finalize_kernel<<<512, 256, 0, stream>>>(rawp, sumsp, ubuf, out0, A2);
        gru_gemm_kernel<<<dim3(24, 8), 256, 0, stream>>>(A2, Bih, Bhh, b_ih, b_hh, gi, gh);
        gru_elem_kernel<<<64, 256, 0, stream>>>(gi, gh, ubuf, slots, A2,
                                                ln_s_g, ln_s_b, qh,
                                                ln_p_g, ln_p_b, P1, it == ITERS - 1 ? 1 : 0);
    }

    // ---- output MLP ----
    hgemm64_kernel<1, 1><<<dim3(16, 4), 256, 0, stream>>>(P1, Bm1, mlp1_b, nullptr, P2, 1024, 1024, 1024);
    hgemm64_kernel<1, 1><<<dim3(16, 4), 256, 0, stream>>>(P2, Bm2, mlp2_b, nullptr, P3, 2048, 1024, 1024);
    hgemm64_kernel<1, 1><<<dim3(8, 4), 256, 0, stream>>>(P3, Bm3, mlp3_b, nullptr, P4, 2048, 512, 512);
    hgemm64_kernel<0, 0><<<dim3(4, 4), 256, 0, stream>>>(P4, Bm4, mlp4_b, out1, nullptr, 1024, 256, 256);
}